// Round 10
// baseline (510.274 us; speedup 1.0000x reference)
//
#include <hip/hip_runtime.h>
#include <math.h>

// ---------------------------------------------------------------------------
// XLSTMCell: gates = [x|h] @ W + b  (16384 x 5120 x 2048 GEMM, bf16 MFMA)
// R10: occupancy experiment. 128x256 tile, BK=32, depth-3 LDS ring (72 KiB)
// -> 2 blocks/CU (vs 1 in R1-R9; all prior schedules stuck at 35-39% MfmaUtil
// because one barrier-lockstep block left the CU idle at every vmcnt/barrier).
// Counted vmcnt(3) keeps 1 tile in flight across the barrier; stage->use lead
// = 2 iterations (~2000cy) >> HBM latency.
// Pre-swizzled global (granule g of each 32-col window of row r at slot
// g^(r&3)) + linear global_load_lds + XOR'd ds_read = conflict-free b128
// (even 8 accesses/bank, verified by bank arithmetic; same scheme as R4/R5
// which measured 0 conflicts with the 64-col/r&7 variant).
// ws layout: A_bf16[16384][2048] | Wt_bf16[5120][2048] | gates[16384][5120]
// ---------------------------------------------------------------------------

typedef unsigned short u16;
typedef unsigned int   u32;
typedef short  short8 __attribute__((ext_vector_type(8)));
typedef float  f32x4  __attribute__((ext_vector_type(4)));
typedef u16    u16x4  __attribute__((ext_vector_type(4)));
typedef u32    u32x4  __attribute__((ext_vector_type(4)));

#define B_ROWS 16384
#define K_DIM  2048
#define N_DIM  5120
#define H_DIM  1024

__device__ __forceinline__ float b2f(u16 u) {
    u32 v = ((u32)u) << 16;
    return __uint_as_float(v);
}
__device__ __forceinline__ u16 f2b(float f) {   // round-to-nearest-even
    u32 x = __float_as_uint(f);
    u32 r = (x + 0x7fffu + ((x >> 16) & 1u)) >> 16;
    return (u16)r;
}
__device__ __forceinline__ float sigm(float v) {
    return 1.f / (1.f + __expf(-v));
}
__device__ __forceinline__ float tanh_fast(float v) {
    v = fminf(fmaxf(v, -15.f), 15.f);
    float e = __expf(-2.f * v);
    return (1.f - e) / (1.f + e);
}

// ---------------------------------------------------------------------------
// 1) pack [x | h_prev] -> bf16 A [16384][2048], PRE-SWIZZLED per 32-col
//    window: granule slot s (8 u16) of row r holds source granule s^(r&3).
// ---------------------------------------------------------------------------
__global__ __launch_bounds__(256) void convert_A(const float* __restrict__ x,
                                                 const float* __restrict__ h,
                                                 u16* __restrict__ A) {
    size_t idx = ((size_t)blockIdx.x * 256 + threadIdx.x) * 8;   // out elem idx
    int row = (int)(idx >> 11);
    int col = (int)(idx & 2047);                 // granule-aligned (col%8==0)
    int srcCol = (col & ~31) | (((((col >> 3) & 3) ^ (row & 3))) << 3);
    const float* src = (srcCol < 1024) ? (x + (size_t)row * 1024 + srcCol)
                                       : (h + (size_t)row * 1024 + (srcCol - 1024));
    f32x4 v0 = *(const f32x4*)src;
    f32x4 v1 = *(const f32x4*)(src + 4);
    u32x4 w;
    w.x = (u32)f2b(v0.x) | ((u32)f2b(v0.y) << 16);
    w.y = (u32)f2b(v0.z) | ((u32)f2b(v0.w) << 16);
    w.z = (u32)f2b(v1.x) | ((u32)f2b(v1.y) << 16);
    w.w = (u32)f2b(v1.z) | ((u32)f2b(v1.w) << 16);
    *(u32x4*)(A + idx) = w;
}

// ---------------------------------------------------------------------------
// 2) W [2048][5120] f32 -> Wt [5120][2048] bf16, transposed + PRE-SWIZZLED
//    (same 32-col-window rule, keyed by n-row & 3).
// ---------------------------------------------------------------------------
__global__ __launch_bounds__(256) void convert_W(const float* __restrict__ W,
                                                 u16* __restrict__ Wt) {
    __shared__ float tile[64][33];      // [k][n]
    const int t  = threadIdx.x;
    const int tx = t & 31;              // n
    const int ty = t >> 5;              // 0..7 (k)
    const int n0 = blockIdx.x * 32;     // 160 blocks
    const int k0 = blockIdx.y * 64;     // 32 blocks
#pragma unroll
    for (int i = 0; i < 8; ++i)
        tile[ty + 8 * i][tx] = W[(size_t)(k0 + ty + 8 * i) * N_DIM + n0 + tx];
    __syncthreads();
    const int n = t >> 3;               // 0..31
    const int s = t & 7;                // output granule slot within 64 cols
    // source k-offset within the 64-col tile: window (s>>2), slot (s&3) holds
    // source granule (s&3)^(n&3)
    const int g8 = ((s >> 2) << 5) + ((((s & 3) ^ (n & 3))) << 3);
    u32x4 w;
    w.x = (u32)f2b(tile[g8 + 0][n]) | ((u32)f2b(tile[g8 + 1][n]) << 16);
    w.y = (u32)f2b(tile[g8 + 2][n]) | ((u32)f2b(tile[g8 + 3][n]) << 16);
    w.z = (u32)f2b(tile[g8 + 4][n]) | ((u32)f2b(tile[g8 + 5][n]) << 16);
    w.w = (u32)f2b(tile[g8 + 6][n]) | ((u32)f2b(tile[g8 + 7][n]) << 16);
    *(u32x4*)(Wt + (size_t)(n0 + n) * K_DIM + k0 + s * 8) = w;
}

// ---------------------------------------------------------------------------
// 3) GEMM: 128x256 tile, BK=32, 512 thr (8 waves 2Mx4N, 64x64 per wave),
//    depth-3 LDS ring.
//    Per iter kt: STAGE(kt+2 -> ring) | 8 ds_read (tile kt) | 16 MFMA |
//    vmcnt(3) | barrier.
//    RAW: reads of tile kt guarded by iter kt-1's vmcnt(3): queue there =
//      [kt's 3][kt+1's 3] -> forces kt's landed; wait precedes barrier =>
//      cross-wave. Tile kt+2's loads stay in flight (counted, never drained).
//    WAR: STAGE at iter kt overwrites the buffer read at iter kt-1; all
//      kt-1 reads were consumed by kt-1's MFMAs (compiler lgkm waits) before
//      the kt-1 closing barrier, and the stage issues after that barrier.
// ---------------------------------------------------------------------------
#define BK 32

__device__ __forceinline__ void gld_lds16(const void* g, void* l) {
    __builtin_amdgcn_global_load_lds(
        (const __attribute__((address_space(1))) void*)g,
        (__attribute__((address_space(3))) void*)l, 16, 0, 0);   // offset MUST be 0
}

#define SB0() __builtin_amdgcn_sched_barrier(0)
#define BAR() do { SB0(); __builtin_amdgcn_s_barrier(); SB0(); } while (0)
#define VM3() asm volatile("s_waitcnt vmcnt(3)" ::: "memory")

__global__ __launch_bounds__(512, 4) void gemm_gates(const u16* __restrict__ A,
                                                     const u16* __restrict__ Bt,
                                                     const float* __restrict__ bias,
                                                     u16* __restrict__ gates) {
    // ring: 3 bufs x (A 4096 + B 8192) u16 = 72 KiB -> 2 blocks/CU
    __shared__ u16 lds[3][12288];

    const int t = threadIdx.x;
    // T1: bijective XCD swizzle (nwg = 2560, 2560 % 8 == 0, cpx = 320).
    // 128 consecutive swz share n0 -> Wt panel (1 MB) L2-resident.
    const int bid = blockIdx.x;
    const int swz = (bid & 7) * 320 + (bid >> 3);
    const int m0 = (swz & 127) << 7;      // 128 M-blocks of 128 rows
    const int n0 = (swz >> 7) << 8;       // 20 N-blocks of 256 cols

    const int l   = t & 63;
    const int wid = t >> 6;
    const int wr  = wid >> 2;             // 0/1  (M half)
    const int wc  = wid & 3;              // 0..3 (N quarter)
    const int lr  = l & 15;
    const int lh  = l >> 4;               // 0..3
    const int slotOff = ((lh ^ (lr & 3)) << 3);   // u16 offset of k-granule

    // staging: thread t -> row t>>2 (0..127), slot t&3 (global pre-swizzled)
    const u16* aBase = A  + (size_t)(m0 + (t >> 2)) * K_DIM + (t & 3) * 8;
    const u16* bBase = Bt + (size_t)(n0 + (t >> 2)) * K_DIM + (t & 3) * 8;
    const int dOff = t * 8;               // u16 (linear LDS dest)

    f32x4 acc[4][4] = {};
    short8 af[4], bf[4];

#define STAGE(Sb, OFF) do {                                                   \
    gld_lds16(aBase + (OFF),                        &lds[Sb][dOff]);          \
    gld_lds16(bBase + (OFF),                        &lds[Sb][4096 + dOff]);   \
    gld_lds16(bBase + (size_t)128 * K_DIM + (OFF),  &lds[Sb][8192 + dOff]);   \
} while (0)

#define BODY(Rb, Sb, kt) do {                                                 \
    const int OFF_ = ((kt) + 2) * BK;                                         \
    STAGE(Sb, OFF_);                                                          \
    _Pragma("unroll") for (int m = 0; m < 4; ++m)                             \
        af[m] = *(const short8*)&lds[Rb][(wr * 64 + m * 16 + lr) * 32 + slotOff];\
    _Pragma("unroll") for (int n = 0; n < 4; ++n)                             \
        bf[n] = *(const short8*)&lds[Rb][4096 + (wc * 64 + n * 16 + lr) * 32 + slotOff];\
    _Pragma("unroll") for (int m = 0; m < 4; ++m)                             \
    _Pragma("unroll") for (int n = 0; n < 4; ++n)                             \
        acc[m][n] = __builtin_amdgcn_mfma_f32_16x16x32_bf16(                  \
            af[m], bf[n], acc[m][n], 0, 0, 0);                                \
    SB0(); VM3();                                                             \
    __builtin_amdgcn_s_barrier(); SB0();                                      \
} while (0)

    // prologue: stage tiles 0,1; vmcnt(3) forces tile 0; barrier (cross-wave)
    STAGE(0, 0);
    STAGE(1, BK);
    SB0(); VM3();
    __builtin_amdgcn_s_barrier(); SB0();

    // 64 K-tiles = 21*3 + 1. Tail stages (tiles 64,65) read benign in-ws
    // garbage (beyond the K extent, inside ws) and are never consumed.
#pragma unroll 1
    for (int it = 0; it < 21; ++it) {
        const int kt = it * 3;
        BODY(0, 2, kt);
        BODY(1, 0, kt + 1);
        BODY(2, 1, kt + 2);
    }
    BODY(0, 2, 63);
#undef STAGE
#undef BODY

    asm volatile("s_waitcnt vmcnt(0)" ::: "memory");   // drain garbage stages

    // epilogue: bias + activation (block's N-tile lies in one gate group)
    const int grp = n0 >> 10;             // 0..4 : f,i,o,c,m
#pragma unroll
    for (int ni = 0; ni < 4; ++ni) {
        int col = n0 + wc * 64 + ni * 16 + lr;
        float bv = bias[col];
#pragma unroll
        for (int m = 0; m < 4; ++m) {
#pragma unroll
            for (int j = 0; j < 4; ++j) {
                int row = m0 + wr * 64 + m * 16 + lh * 4 + j;
                float v = acc[m][ni][j] + bv;
                float g = (grp == 3) ? tanh_fast(v) : sigm(v);
                gates[(size_t)row * N_DIM + col] = f2b(g);
            }
        }
    }
}

// ---------------------------------------------------------------------------
// 4) per-row: LN stats over o, cell update, outputs
// ---------------------------------------------------------------------------
__global__ __launch_bounds__(256) void fuse_out(const u16* __restrict__ gates,
                                                const float* __restrict__ c_prev,
                                                const float* __restrict__ ret,
                                                const float* __restrict__ gamma,
                                                const float* __restrict__ beta,
                                                float* __restrict__ out) {
    const int r = blockIdx.x;
    const int t = threadIdx.x;
    const u16* g = gates + (size_t)r * N_DIM;
    const int j0 = t * 4;

    // o = sigmoid(o_pre) already; LN stats over the row of 1024
    u16x4 ov = *(const u16x4*)(g + 2048 + j0);
    float o0 = b2f(ov.x), o1 = b2f(ov.y), o2 = b2f(ov.z), o3 = b2f(ov.w);
    float s1 = o0 + o1 + o2 + o3;
    float s2 = o0 * o0 + o1 * o1 + o2 * o2 + o3 * o3;
#pragma unroll
    for (int off = 32; off; off >>= 1) {
        s1 += __shfl_xor(s1, off, 64);
        s2 += __shfl_xor(s2, off, 64);
    }
    __shared__ float red[8];
    if ((t & 63) == 0) { red[t >> 6] = s1; red[4 + (t >> 6)] = s2; }
    __syncthreads();
    float S1 = red[0] + red[1] + red[2] + red[3];
    float S2 = red[4] + red[5] + red[6] + red[7];
    float mu   = S1 * (1.f / 1024.f);
    float var  = S2 * (1.f / 1024.f) - mu * mu;
    float rstd = rsqrtf(var + 1e-5f);

    u16x4 fv = *(const u16x4*)(g + j0);
    u16x4 iv = *(const u16x4*)(g + 1024 + j0);
    u16x4 cv = *(const u16x4*)(g + 3072 + j0);
    u16x4 mv = *(const u16x4*)(g + 4096 + j0);
    f32x4 cp = *(const f32x4*)(c_prev + (size_t)r * H_DIM + j0);
    f32x4 rt = *(const f32x4*)(ret + j0);
    f32x4 gm = *(const f32x4*)(gamma + j0);
    f32x4 bt = *(const f32x4*)(beta + j0);

    float of[4] = {o0, o1, o2, o3};
    u16 fa[4] = {fv.x, fv.y, fv.z, fv.w};
    u16 ia[4] = {iv.x, iv.y, iv.z, iv.w};
    u16 ca[4] = {cv.x, cv.y, cv.z, cv.w};
    u16 ma[4] = {mv.x, mv.y, mv.z, mv.w};

    f32x4 hout, cout;
#pragma unroll
    for (int i = 0; i < 4; ++i) {
        float f = b2f(fa[i]), ig = b2f(ia[i]), cc = b2f(ca[i]), m = b2f(ma[i]);
        float cpv = cp[i], rv = rt[i];
        float c1 = f * cpv + ig * cc;
        float c2 = c1 * rv + (1.f - rv) * cpv;
        float cn = m * c2 + (1.f - m) * cpv;
        float ln = (of[i] - mu) * rstd * gm[i] + bt[i];
        float oe = sigm(ln);
        float hn = oe * tanh_fast(cn);
        hout[i] = hn;
        cout[i] = cn;
    }
    *(f32x4*)(out + (size_t)r * H_DIM + j0) = hout;
    *(f32x4*)(out + (size_t)B_ROWS * H_DIM + (size_t)r * H_DIM + j0) = cout;
}

// ---------------------------------------------------------------------------
extern "C" void kernel_launch(void* const* d_in, const int* in_sizes, int n_in,
                              void* d_out, int out_size, void* d_ws, size_t ws_size,
                              hipStream_t stream) {
    const float* x      = (const float*)d_in[0];
    const float* h_prev = (const float*)d_in[1];
    const float* c_prev = (const float*)d_in[2];
    const float* W      = (const float*)d_in[3];
    const float* bias   = (const float*)d_in[4];
    const float* gamma  = (const float*)d_in[5];
    const float* beta   = (const float*)d_in[6];
    const float* ret    = (const float*)d_in[7];
    float* out = (float*)d_out;

    u16* Abuf  = (u16*)d_ws;                             // [16384][2048]
    u16* Wt    = Abuf + (size_t)B_ROWS * K_DIM;          // [5120][2048]
    u16* gates = Wt + (size_t)N_DIM * K_DIM;             // [16384][5120]

    convert_A<<<(B_ROWS * K_DIM / 8) / 256, 256, 0, stream>>>(x, h_prev, Abuf);
    convert_W<<<dim3(N_DIM / 32, K_DIM / 64), 256, 0, stream>>>(W, Wt);
    gemm_gates<<<(B_ROWS / 128) * (N_DIM / 256), 512, 0, stream>>>(Abuf, Wt, bias, gates);
    fuse_out<<<B_ROWS, 256, 0, stream>>>(gates, c_prev, ret, gamma, beta, out);
}

// Round 11
// 482.470 us; speedup vs baseline: 1.0576x; 1.0576x over previous
//
#include <hip/hip_runtime.h>
#include <math.h>

// ---------------------------------------------------------------------------
// XLSTMCell: gates = [x|h] @ W + b  (16384 x 5120 x 2048 GEMM, bf16 MFMA)
// R11 = R5's proven 8-phase kernel + ONE new mechanism: A-fragment reads
// pipelined one phase ahead (P4 pre-reads next tile's q0 fragments into afN,
// so P1's MFMA starts without an 8-read in-phase burst). vmcnt(4) at end of
// EVERY phase; FIFO audit (stage order per tile kt: P1:A0' P2:B0' P3:B1'
// P4:A1', all for tile kt+1; 2 loads each):
//   end-P1 forces (kt-1)S3 = B1(kt)  -> P2's bf1 read OK
//   end-P2 forces (kt-1)S4 = A1(kt)  -> P3's afC read OK
//   end-P3 forces (kt)S1  = A0(kt+1) -> P4's afN pre-read OK
//   end-P4 forces (kt)S2  = B0(kt+1) -> next P1's bf0 read OK
// Each wait precedes a barrier => cross-wave guarantee. All leads >= 2 phases.
// WAR: every unit overwrite is >= 4 barriers after its last LDS read.
// NO lgkmcnt(0) in P4 (would serialize the afN pre-read; P4's MFMA operands
// were lgkm-waited in P1/P3). offset arg of global_load_lds MUST be 0
// (applies to BOTH addresses - R6-R8 root cause).
// ws layout: A_bf16[16384][2048] | Wt_bf16[5120][2048] | gates[16384][5120]
// ---------------------------------------------------------------------------

typedef unsigned short u16;
typedef unsigned int   u32;
typedef short  short8 __attribute__((ext_vector_type(8)));
typedef float  f32x4  __attribute__((ext_vector_type(4)));
typedef u16    u16x4  __attribute__((ext_vector_type(4)));
typedef u32    u32x4  __attribute__((ext_vector_type(4)));

#define B_ROWS 16384
#define K_DIM  2048
#define N_DIM  5120
#define H_DIM  1024

__device__ __forceinline__ float b2f(u16 u) {
    u32 v = ((u32)u) << 16;
    return __uint_as_float(v);
}
__device__ __forceinline__ u16 f2b(float f) {   // round-to-nearest-even
    u32 x = __float_as_uint(f);
    u32 r = (x + 0x7fffu + ((x >> 16) & 1u)) >> 16;
    return (u16)r;
}
__device__ __forceinline__ float sigm(float v) {
    return 1.f / (1.f + __expf(-v));
}
__device__ __forceinline__ float tanh_fast(float v) {
    v = fminf(fmaxf(v, -15.f), 15.f);
    float e = __expf(-2.f * v);
    return (1.f - e) / (1.f + e);
}

// ---------------------------------------------------------------------------
// 1) pack [x | h_prev] -> bf16 A [16384][2048], PRE-SWIZZLED:
//    granule slot s of each 64-elem K-window of row r holds granule s^(r&7).
// ---------------------------------------------------------------------------
__global__ __launch_bounds__(256) void convert_A(const float* __restrict__ x,
                                                 const float* __restrict__ h,
                                                 u16* __restrict__ A) {
    size_t idx = ((size_t)blockIdx.x * 256 + threadIdx.x) * 8;   // out elem idx
    int row = (int)(idx >> 11);
    int col = (int)(idx & 2047);                 // granule-aligned (col%8==0)
    int srcCol = (col & ~63) | (((((col >> 3) & 7) ^ (row & 7))) << 3);
    const float* src = (srcCol < 1024) ? (x + (size_t)row * 1024 + srcCol)
                                       : (h + (size_t)row * 1024 + (srcCol - 1024));
    f32x4 v0 = *(const f32x4*)src;
    f32x4 v1 = *(const f32x4*)(src + 4);
    u32x4 w;
    w.x = (u32)f2b(v0.x) | ((u32)f2b(v0.y) << 16);
    w.y = (u32)f2b(v0.z) | ((u32)f2b(v0.w) << 16);
    w.z = (u32)f2b(v1.x) | ((u32)f2b(v1.y) << 16);
    w.w = (u32)f2b(v1.z) | ((u32)f2b(v1.w) << 16);
    *(u32x4*)(A + idx) = w;
}

// ---------------------------------------------------------------------------
// 2) W [2048][5120] f32 -> Wt [5120][2048] bf16, transposed + PRE-SWIZZLED
//    (same granule rule, keyed by n-row & 7).
// ---------------------------------------------------------------------------
__global__ __launch_bounds__(256) void convert_W(const float* __restrict__ W,
                                                 u16* __restrict__ Wt) {
    __shared__ float tile[64][33];      // [k][n]
    const int t  = threadIdx.x;
    const int tx = t & 31;              // n
    const int ty = t >> 5;              // 0..7 (k)
    const int n0 = blockIdx.x * 32;     // 160 blocks
    const int k0 = blockIdx.y * 64;     // 32 blocks
#pragma unroll
    for (int i = 0; i < 8; ++i)
        tile[ty + 8 * i][tx] = W[(size_t)(k0 + ty + 8 * i) * N_DIM + n0 + tx];
    __syncthreads();
    const int n = t >> 3;               // 0..31
    const int s = t & 7;                // output granule slot
    const int g = s ^ (n & 7);          // source granule ((n0+n)&7 == n&7)
    u32x4 w;
    w.x = (u32)f2b(tile[g * 8 + 0][n]) | ((u32)f2b(tile[g * 8 + 1][n]) << 16);
    w.y = (u32)f2b(tile[g * 8 + 2][n]) | ((u32)f2b(tile[g * 8 + 3][n]) << 16);
    w.z = (u32)f2b(tile[g * 8 + 4][n]) | ((u32)f2b(tile[g * 8 + 5][n]) << 16);
    w.w = (u32)f2b(tile[g * 8 + 6][n]) | ((u32)f2b(tile[g * 8 + 7][n]) << 16);
    *(u32x4*)(Wt + (size_t)(n0 + n) * K_DIM + k0 + s * 8) = w;
}

// ---------------------------------------------------------------------------
// 3) GEMM: 256x256, BK=64, 512 thr (8 waves 2Mx4N), 8-phase pipeline with
//    one-phase-ahead A-fragment reads (afN). Units: A[s][h] = tile rows
//    bit6==h; B[s][h] = n-rows bit5==h.
// ---------------------------------------------------------------------------
#define BK 64

__device__ __forceinline__ void gld_lds16(const void* g, void* l) {
    __builtin_amdgcn_global_load_lds(
        (const __attribute__((address_space(1))) void*)g,
        (__attribute__((address_space(3))) void*)l, 16, 0, 0);   // offset MUST be 0
}

#define AU(s, h) ((s) * 16384 + (h) * 8192)            // u16 index of A unit
#define BU(s, h) (32768 + (s) * 16384 + (h) * 8192)    // u16 index of B unit

#define BAR() do { __builtin_amdgcn_sched_barrier(0);                         \
                   __builtin_amdgcn_s_barrier();                              \
                   __builtin_amdgcn_sched_barrier(0); } while (0)
#define LGKM0() do { asm volatile("s_waitcnt lgkmcnt(0)" ::: "memory");       \
                     __builtin_amdgcn_sched_barrier(0); } while (0)
#define VM4() asm volatile("s_waitcnt vmcnt(4)" ::: "memory")

__global__ __launch_bounds__(512, 2) void gemm_gates(const u16* __restrict__ A,
                                                     const u16* __restrict__ Bt,
                                                     const float* __restrict__ bias,
                                                     u16* __restrict__ gates) {
    __shared__ u16 lds[65536];            // 128 KiB

    const int t = threadIdx.x;
    // T1: bijective XCD swizzle (nwg = 1280, 1280 % 8 == 0)
    const int bid = blockIdx.x;
    const int swz = (bid & 7) * 160 + (bid >> 3);
    const int m0 = (swz & 63) << 8;       // 64 M-blocks
    const int n0 = (swz >> 6) << 8;       // 20 N-blocks

    const int l   = t & 63;
    const int wid = t >> 6;
    const int wr  = wid >> 2;             // 0/1  (M)
    const int wc  = wid & 3;              // 0..3 (N)
    const int lr  = l & 15;
    const int lh  = l >> 4;
    const int z   = lr & 7;
    const int sA0 = (lh ^ z) * 8;         // sk=0 granule slot offset (u16)

    // staging bases: thread t -> row t>>3, granule t&7 (global pre-swizzled)
    const int tb = t >> 3;                // 0..63
    const u16* aBase = A  + (size_t)(m0 + tb) * K_DIM + (t & 7) * 8;
    const u16* bBase = Bt + (size_t)(n0 + (tb & 31) + (tb >> 5) * 64) * K_DIM
                          + (t & 7) * 8;
    const int dOff = t * 8;               // u16

    f32x4 acc[8][4] = {};
    short8 afN[4][2], afC[4][2], bf0[2][2], bf1[2][2];

#define STAGE_A(s, h, OFF) do {                                               \
    gld_lds16(aBase + (size_t)((h) * 64) * K_DIM + (OFF),                     \
              &lds[AU(s, h) + dOff]);                                         \
    gld_lds16(aBase + (size_t)((h) * 64 + 128) * K_DIM + (OFF),               \
              &lds[AU(s, h) + 4096 + dOff]);                                  \
} while (0)
#define STAGE_B(s, h, OFF) do {                                               \
    gld_lds16(bBase + (size_t)((h) * 32) * K_DIM + (OFF),                     \
              &lds[BU(s, h) + dOff]);                                         \
    gld_lds16(bBase + (size_t)((h) * 32 + 128) * K_DIM + (OFF),               \
              &lds[BU(s, h) + 4096 + dOff]);                                  \
} while (0)

#define RD_AFX(dst, s, q) do {                                                \
    _Pragma("unroll") for (int m = 0; m < 4; ++m) {                           \
        const int u_ = AU(s, q) + (wr * 64 + m * 16 + lr) * 64;               \
        dst[m][0] = *(const short8*)&lds[u_ + sA0];                           \
        dst[m][1] = *(const short8*)&lds[u_ + (sA0 ^ 32)];                    \
    }                                                                         \
} while (0)
#define RD_BF(dst, s, h) do {                                                 \
    _Pragma("unroll") for (int n = 0; n < 2; ++n) {                           \
        const int u_ = BU(s, h) + (wc * 32 + n * 16 + lr) * 64;               \
        dst[n][0] = *(const short8*)&lds[u_ + sA0];                           \
        dst[n][1] = *(const short8*)&lds[u_ + (sA0 ^ 32)];                    \
    }                                                                         \
} while (0)

#define MFMA16(AF, q, nh, BF) do {                                            \
    __builtin_amdgcn_s_setprio(1);                                            \
    _Pragma("unroll") for (int sk = 0; sk < 2; ++sk)                          \
    _Pragma("unroll") for (int m = 0; m < 4; ++m)                             \
    _Pragma("unroll") for (int n = 0; n < 2; ++n)                             \
        acc[(q) * 4 + m][(nh) * 2 + n] =                                      \
            __builtin_amdgcn_mfma_f32_16x16x32_bf16(                          \
                AF[m][sk], BF[n][sk], acc[(q) * 4 + m][(nh) * 2 + n], 0, 0, 0);\
    __builtin_amdgcn_s_setprio(0);                                            \
} while (0)

    // prologue: stage tile 0 fully, drain, sync, pre-read afN (tile 0 q0).
    STAGE_A(0, 0, 0); STAGE_B(0, 0, 0); STAGE_B(0, 1, 0); STAGE_A(0, 1, 0);
    asm volatile("s_waitcnt vmcnt(0)" ::: "memory");
    BAR();
    RD_AFX(afN, 0, 0);

#pragma unroll 1
    for (int kt = 0; kt < 32; ++kt) {
        const int s  = kt & 1;
        const int sp = s ^ 1;
        const int OFF = (kt + 1) * BK;    // kt=31: benign in-ws OOB, never used
        // P1: MFMA q0 x n01 (afN pre-read last P4; bf0 read now, 4 reads)
        RD_BF(bf0, s, 0); STAGE_A(sp, 0, OFF);
        BAR(); LGKM0(); MFMA16(afN, 0, 0, bf0); VM4(); BAR();
        // P2: MFMA q0 x n23 (bf1 read now, 4 reads)
        RD_BF(bf1, s, 1); STAGE_B(sp, 0, OFF);
        BAR(); LGKM0(); MFMA16(afN, 0, 1, bf1); VM4(); BAR();
        // P3: MFMA q1 x n23 (afC read now, 8 reads — in-phase, reg budget)
        RD_AFX(afC, s, 1); STAGE_B(sp, 1, OFF);
        BAR(); LGKM0(); MFMA16(afC, 1, 1, bf1); VM4(); BAR();
        // P4: pre-read NEXT tile's q0 into afN (A[sp][0], forced by end-P3's
        // vmcnt); NO lgkm drain — afN waits happen at next P1's LGKM0.
        RD_AFX(afN, sp, 0); STAGE_A(sp, 1, OFF);
        BAR(); MFMA16(afC, 1, 0, bf0); VM4(); BAR();
    }
#undef STAGE_A
#undef STAGE_B

    asm volatile("s_waitcnt vmcnt(0)" ::: "memory");   // drain garbage stages

    // epilogue: bias + activation (R5 scalar form; block's N-tile in 1 group)
    const int grp = n0 >> 10;             // 0..4 : f,i,o,c,m
#pragma unroll
    for (int ni = 0; ni < 4; ++ni) {
        int col = n0 + wc * 64 + ni * 16 + lr;
        float bv = bias[col];
#pragma unroll
        for (int q = 0; q < 2; ++q) {
#pragma unroll
            for (int m = 0; m < 4; ++m) {
#pragma unroll
                for (int j = 0; j < 4; ++j) {
                    int row = m0 + wr * 128 + q * 64 + m * 16 + lh * 4 + j;
                    float v = acc[q * 4 + m][ni][j] + bv;
                    float g = (grp == 3) ? tanh_fast(v) : sigm(v);
                    gates[(size_t)row * N_DIM + col] = f2b(g);
                }
            }
        }
    }
#undef RD_AFX
#undef RD_BF
#undef MFMA16
}

// ---------------------------------------------------------------------------
// 4) per-row: LN stats over o, cell update, outputs
// ---------------------------------------------------------------------------
__global__ __launch_bounds__(256) void fuse_out(const u16* __restrict__ gates,
                                                const float* __restrict__ c_prev,
                                                const float* __restrict__ ret,
                                                const float* __restrict__ gamma,
                                                const float* __restrict__ beta,
                                                float* __restrict__ out) {
    const int r = blockIdx.x;
    const int t = threadIdx.x;
    const u16* g = gates + (size_t)r * N_DIM;
    const int j0 = t * 4;

    // o = sigmoid(o_pre) already; LN stats over the row of 1024
    u16x4 ov = *(const u16x4*)(g + 2048 + j0);
    float o0 = b2f(ov.x), o1 = b2f(ov.y), o2 = b2f(ov.z), o3 = b2f(ov.w);
    float s1 = o0 + o1 + o2 + o3;
    float s2 = o0 * o0 + o1 * o1 + o2 * o2 + o3 * o3;
#pragma unroll
    for (int off = 32; off; off >>= 1) {
        s1 += __shfl_xor(s1, off, 64);
        s2 += __shfl_xor(s2, off, 64);
    }
    __shared__ float red[8];
    if ((t & 63) == 0) { red[t >> 6] = s1; red[4 + (t >> 6)] = s2; }
    __syncthreads();
    float S1 = red[0] + red[1] + red[2] + red[3];
    float S2 = red[4] + red[5] + red[6] + red[7];
    float mu   = S1 * (1.f / 1024.f);
    float var  = S2 * (1.f / 1024.f) - mu * mu;
    float rstd = rsqrtf(var + 1e-5f);

    u16x4 fv = *(const u16x4*)(g + j0);
    u16x4 iv = *(const u16x4*)(g + 1024 + j0);
    u16x4 cv = *(const u16x4*)(g + 3072 + j0);
    u16x4 mv = *(const u16x4*)(g + 4096 + j0);
    f32x4 cp = *(const f32x4*)(c_prev + (size_t)r * H_DIM + j0);
    f32x4 rt = *(const f32x4*)(ret + j0);
    f32x4 gm = *(const f32x4*)(gamma + j0);
    f32x4 bt = *(const f32x4*)(beta + j0);

    float of[4] = {o0, o1, o2, o3};
    u16 fa[4] = {fv.x, fv.y, fv.z, fv.w};
    u16 ia[4] = {iv.x, iv.y, iv.z, iv.w};
    u16 ca[4] = {cv.x, cv.y, cv.z, cv.w};
    u16 ma[4] = {mv.x, mv.y, mv.z, mv.w};

    f32x4 hout, cout;
#pragma unroll
    for (int i = 0; i < 4; ++i) {
        float f = b2f(fa[i]), ig = b2f(ia[i]), cc = b2f(ca[i]), m = b2f(ma[i]);
        float cpv = cp[i], rv = rt[i];
        float c1 = f * cpv + ig * cc;
        float c2 = c1 * rv + (1.f - rv) * cpv;
        float cn = m * c2 + (1.f - m) * cpv;
        float ln = (of[i] - mu) * rstd * gm[i] + bt[i];
        float oe = sigm(ln);
        float hn = oe * tanh_fast(cn);
        hout[i] = hn;
        cout[i] = cn;
    }
    *(f32x4*)(out + (size_t)r * H_DIM + j0) = hout;
    *(f32x4*)(out + (size_t)B_ROWS * H_DIM + (size_t)r * H_DIM + j0) = cout;
}

// ---------------------------------------------------------------------------
extern "C" void kernel_launch(void* const* d_in, const int* in_sizes, int n_in,
                              void* d_out, int out_size, void* d_ws, size_t ws_size,
                              hipStream_t stream) {
    const float* x      = (const float*)d_in[0];
    const float* h_prev = (const float*)d_in[1];
    const float* c_prev = (const float*)d_in[2];
    const float* W      = (const float*)d_in[3];
    const float* bias   = (const float*)d_in[4];
    const float* gamma  = (const float*)d_in[5];
    const float* beta   = (const float*)d_in[6];
    const float* ret    = (const float*)d_in[7];
    float* out = (float*)d_out;

    u16* Abuf  = (u16*)d_ws;                             // [16384][2048]
    u16* Wt    = Abuf + (size_t)B_ROWS * K_DIM;          // [5120][2048]
    u16* gates = Wt + (size_t)N_DIM * K_DIM;             // [16384][5120]

    convert_A<<<(B_ROWS * K_DIM / 8) / 256, 256, 0, stream>>>(x, h_prev, Abuf);
    convert_W<<<dim3(N_DIM / 32, K_DIM / 64), 256, 0, stream>>>(W, Wt);
    gemm_gates<<<(B_ROWS / 256) * (N_DIM / 256), 512, 0, stream>>>(Abuf, Wt, bias, gates);
    fuse_out<<<B_ROWS, 256, 0, stream>>>(gates, c_prev, ret, gamma, beta, out);
}